// Round 11
// baseline (123.134 us; speedup 1.0000x reference)
//
#include <hip/hip_runtime.h>

#define NB 2
#define NH 8
#define NS 2048
#define ND 64
#define WKT 32              // keys per wave-tile
#define NTW 16              // tiles per wave per pass (2048 / (32*4))
#define QST 68              // LDS strides (f16 elems; rows 8B-aligned)
#define VST 36
#define PST 36
#define OST 68              // f32

typedef _Float16 f16x4 __attribute__((ext_vector_type(4)));
typedef _Float16 f16x8 __attribute__((ext_vector_type(8)));
typedef float    f32x4 __attribute__((ext_vector_type(4)));

#define MFMA16(A,B,C) __builtin_amdgcn_mfma_f32_16x16x32_f16((A),(B),(C),0,0,0)

static __device__ __forceinline__ f16x8 cat8(f16x4 a, f16x4 b) {
    return __builtin_shufflevector(a, b, 0, 1, 2, 3, 4, 5, 6, 7);
}
static __device__ __forceinline__ f16x4 tof16(float4 f) {
    return (f16x4){ (_Float16)f.x, (_Float16)f.y, (_Float16)f.z, (_Float16)f.w };
}
static __device__ __forceinline__ f16x8 lds8(const _Float16* p) {
    f16x4 a = *(const f16x4*)p;          // ds_read_b64 pair
    f16x4 b = *(const f16x4*)(p + 4);
    return cat8(a, b);
}

__global__ __launch_bounds__(256, 2)
void sdpa_kernel(const float* __restrict__ Qg, const float* __restrict__ Kg,
                 const float* __restrict__ Vg, float* __restrict__ Og,
                 float* __restrict__ Ag)
{
    const int tid  = threadIdx.x;
    const int w    = tid >> 6;
    const int lane = tid & 63;
    const int lg   = lane >> 4;
    const int lc   = lane & 15;

    // XCD-pinned decode (proven: FETCH 103->12 MB): bid&7 = XCD, 2 heads per XCD.
    const int bid = blockIdx.x;
    const int xcd = bid & 7;
    const int j   = bid >> 3;           // 0..63
    const int bh  = 2 * xcd + (j >> 5); // 0..15
    const int qt_ = j & 31;             // 0..31

    const size_t base = (size_t)bh * NS * ND;
    const float* Qp = Qg + base + (size_t)qt_ * 64 * ND;
    const float* Kp = Kg + base;
    const float* Vp = Vg + base;
    float*       Op = Og + base + (size_t)qt_ * 64 * ND;
    float*       Ap = Ag + (size_t)bh * NS * NS + (size_t)qt_ * 64 * NS;

    // LDS: VT[w] 4608 | Ps[w] 4608 | MLs 1024; Qs (prologue) and Obuf
    // (epilogue) overlay the VT region. Total 37888 B.
    __shared__ __align__(16) unsigned char pool[37888];
    _Float16* Qs = (_Float16*)pool;                            // prologue only
    _Float16* VT = (_Float16*)(pool + (size_t)w * 4608);
    _Float16* Ps = (_Float16*)(pool + 18432 + (size_t)w * 4608);
    float*   MLs = (float*)(pool + 36864);                     // inter-pass
    float*  Obuf = (float*)pool;                               // epilogue

    // ---- stage Q (scaled by 1/T = 1/8, exact) cooperatively ----
    {
        const int srow = tid >> 4, sd0 = (tid & 15) * 4;
        #pragma unroll
        for (int it = 0; it < 4; ++it) {
            const int r = srow + 16 * it;
            float4 f = *(const float4*)&Qp[(size_t)r * ND + sd0];
            f16x4 h = { (_Float16)(f.x * 0.125f), (_Float16)(f.y * 0.125f),
                        (_Float16)(f.z * 0.125f), (_Float16)(f.w * 0.125f) };
            *(f16x4*)&Qs[r * QST + sd0] = h;
        }
    }
    __syncthreads();
    f16x8 qfa[4], qfb[4];        // every wave needs all 64 q columns
    #pragma unroll
    for (int qt = 0; qt < 4; ++qt) {
        qfa[qt] = lds8(&Qs[(16 * qt + lc) * QST + 8 * lg]);
        qfb[qt] = lds8(&Qs[(16 * qt + lc) * QST + 8 * lg + 32]);
    }
    __syncthreads();             // Qs dead; VT overlays it

    const int vkq = lane >> 3;   // V staging: key quad 4*vkq
    const int vdg = lane & 7;    // V staging: d group 8*vdg

    // K direct-to-fragment loads: lane (lg,lc) reads K[koff+16mt+lc][cols]
    float4 kt0[8], kt1[8];
    auto loadKd = [&](float4 (&kt)[8], int t) {
        const int koff = (4 * t + w) * WKT;
        #pragma unroll
        for (int mt = 0; mt < 2; ++mt) {
            const float* rp = &Kp[(size_t)(koff + 16 * mt + lc) * ND + 8 * lg];
            kt[4 * mt + 0] = *(const float4*)(rp);
            kt[4 * mt + 1] = *(const float4*)(rp + 4);
            kt[4 * mt + 2] = *(const float4*)(rp + 32);
            kt[4 * mt + 3] = *(const float4*)(rp + 36);
        }
    };
    auto cvtK = [&](const float4 (&kt)[8], f16x8 (&kf)[4]) {
        #pragma unroll
        for (int mt = 0; mt < 2; ++mt) {
            kf[2 * mt + 0] = cat8(tof16(kt[4 * mt + 0]), tof16(kt[4 * mt + 1]));
            kf[2 * mt + 1] = cat8(tof16(kt[4 * mt + 2]), tof16(kt[4 * mt + 3]));
        }
    };

    float lacc[4] = {0.f, 0.f, 0.f, 0.f};

    // ============ PASS A: denominators (LDS-free, K-prefetched) ============
    auto bodyA = [&](const float4 (&cur)[8], float4 (&nxt)[8], int t) {
        f16x8 kf[4];
        cvtK(cur, kf);
        loadKd(nxt, t + 1 < NTW ? t + 1 : 0);
        __builtin_amdgcn_s_setprio(1);
        f32x4 z[2][4];
        #pragma unroll
        for (int mt = 0; mt < 2; ++mt)
            #pragma unroll
            for (int qt = 0; qt < 4; ++qt) {
                f32x4 zz = {0.f, 0.f, 0.f, 0.f};
                zz = MFMA16(kf[2 * mt], qfa[qt], zz);
                zz = MFMA16(kf[2 * mt + 1], qfb[qt], zz);
                z[mt][qt] = zz;
            }
        __builtin_amdgcn_s_setprio(0);
        #pragma unroll
        for (int mt = 0; mt < 2; ++mt)
            #pragma unroll
            for (int qt = 0; qt < 4; ++qt)
                #pragma unroll
                for (int r = 0; r < 4; ++r)
                    lacc[qt] += __expf(z[mt][qt][r]);
    };
    loadKd(kt0, 0);
    for (int t = 0; t < NTW; t += 2) {
        bodyA(kt0, kt1, t);
        bodyA(kt1, kt0, t + 1);
    }

    // ---- merge denominators across waves (max-free softmax) ----
    #pragma unroll
    for (int qt = 0; qt < 4; ++qt) {
        lacc[qt] += __shfl_xor(lacc[qt], 16);
        lacc[qt] += __shfl_xor(lacc[qt], 32);
    }
    if (lg == 0) {
        #pragma unroll
        for (int qt = 0; qt < 4; ++qt)
            MLs[w * 64 + 16 * qt + lc] = lacc[qt];
    }
    __syncthreads();
    float il[4];
    #pragma unroll
    for (int qt = 0; qt < 4; ++qt)
        il[qt] = 1.0f / (MLs[16 * qt + lc] + MLs[64 + 16 * qt + lc] +
                         MLs[128 + 16 * qt + lc] + MLs[192 + 16 * qt + lc]);
    __syncthreads();

    // ============ PASS B: attn write + PV ============
    f32x4 acc[4][4];             // [dt][qt]
    #pragma unroll
    for (int dt = 0; dt < 4; ++dt)
        #pragma unroll
        for (int qt = 0; qt < 4; ++qt)
            acc[dt][qt] = {0.f, 0.f, 0.f, 0.f};

    float4 vt[8];
    auto loadV = [&](int t) {
        const int koff = (4 * t + w) * WKT;
        #pragma unroll
        for (int r = 0; r < 4; ++r)
            #pragma unroll
            for (int h = 0; h < 2; ++h)
                vt[2 * r + h] = *(const float4*)
                    &Vp[(size_t)(koff + 4 * vkq + r) * ND + 8 * vdg + 4 * h];
    };
    auto writeVT = [&]() {       // 4x4 in-register transpose -> b64 writes
        #pragma unroll
        for (int h = 0; h < 2; ++h)
            #pragma unroll
            for (int jj = 0; jj < 4; ++jj) {
                f16x4 col = { (_Float16)vt[0 + h][jj], (_Float16)vt[2 + h][jj],
                              (_Float16)vt[4 + h][jj], (_Float16)vt[6 + h][jj] };
                *(f16x4*)&VT[(8 * vdg + 4 * h + jj) * VST + 4 * vkq] = col;
            }
    };

    auto bodyB = [&](const float4 (&cur)[8], float4 (&nxt)[8], int t) {
        const int koff = (4 * t + w) * WKT;
        loadV(t);                                  // in-tile V prefetch
        f16x8 kf[4];
        cvtK(cur, kf);
        loadKd(nxt, t + 1 < NTW ? t + 1 : 0);      // cross-tile K prefetch

        f32x4 s[2][4];
        __builtin_amdgcn_s_setprio(1);
        #pragma unroll
        for (int mt = 0; mt < 2; ++mt)
            #pragma unroll
            for (int qt = 0; qt < 4; ++qt) {
                f32x4 zz = {0.f, 0.f, 0.f, 0.f};
                zz = MFMA16(kf[2 * mt], qfa[qt], zz);
                zz = MFMA16(kf[2 * mt + 1], qfb[qt], zz);
                s[mt][qt] = zz;
            }
        __builtin_amdgcn_s_setprio(0);

        #pragma unroll
        for (int mt = 0; mt < 2; ++mt)
            #pragma unroll
            for (int qt = 0; qt < 4; ++qt) {
                f32x4 p;
                #pragma unroll
                for (int r = 0; r < 4; ++r)
                    p[r] = __expf(s[mt][qt][r]) * il[qt];
                __builtin_nontemporal_store(p,
                    (f32x4*)&Ap[(size_t)(16 * qt + lc) * NS + koff + 16 * mt + 4 * lg]);
                f16x4 ph = { (_Float16)p[0], (_Float16)p[1],
                             (_Float16)p[2], (_Float16)p[3] };
                *(f16x4*)&Ps[(16 * qt + lc) * PST + 16 * mt + 4 * lg] = ph;
            }
        writeVT();                                 // V arrived during QK/exp

        asm volatile("s_waitcnt lgkmcnt(0)" ::: "memory");  // P+VT RAW (wave-local)
        __builtin_amdgcn_sched_barrier(0);

        f16x8 bf[4];
        #pragma unroll
        for (int qt = 0; qt < 4; ++qt)
            bf[qt] = lds8(&Ps[(16 * qt + lc) * PST + 8 * lg]);
        __builtin_amdgcn_s_setprio(1);
        #pragma unroll
        for (int dt = 0; dt < 4; ++dt) {
            f16x8 af = lds8(&VT[(16 * dt + lc) * VST + 8 * lg]);
            #pragma unroll
            for (int qt = 0; qt < 4; ++qt)
                acc[dt][qt] = MFMA16(af, bf[qt], acc[dt][qt]);
        }
        __builtin_amdgcn_s_setprio(0);
    };

    loadKd(kt0, 0);
    for (int t = 0; t < NTW; t += 2) {
        bodyB(kt0, kt1, t);
        bodyB(kt1, kt0, t + 1);
    }

    // ---- merge partial O across waves (sequential LDS accumulate), store ----
    __syncthreads();             // main-loop LDS dead; Obuf overlays
    #pragma unroll
    for (int ww = 0; ww < 4; ++ww) {
        if (w == ww) {
            #pragma unroll
            for (int dt = 0; dt < 4; ++dt)
                #pragma unroll
                for (int qt = 0; qt < 4; ++qt) {
                    float* ad = &Obuf[(16 * qt + lc) * OST + 16 * dt + 4 * lg];
                    f32x4 v = acc[dt][qt];
                    if (ww > 0) v = v + *(const f32x4*)ad;
                    *(f32x4*)ad = v;
                }
        }
        __syncthreads();
    }
    #pragma unroll
    for (int dt = 0; dt < 4; ++dt) {
        f32x4 o = *(const f32x4*)&Obuf[(16 * w + lc) * OST + 16 * dt + 4 * lg];
        __builtin_nontemporal_store(o,
            (f32x4*)&Op[(size_t)(16 * w + lc) * ND + 16 * dt + 4 * lg]);
    }
}

extern "C" void kernel_launch(void* const* d_in, const int* in_sizes, int n_in,
                              void* d_out, int out_size, void* d_ws, size_t ws_size,
                              hipStream_t stream) {
    const float* q = (const float*)d_in[0];
    const float* k = (const float*)d_in[1];
    const float* v = (const float*)d_in[2];
    float* out  = (float*)d_out;
    float* attn = out + (size_t)NB * NH * NS * ND;  // outputs: (output, attn)

    sdpa_kernel<<<dim3((NS / 64) * NB * NH), 256, 0, stream>>>(q, k, v, out, attn);
}

// Round 12
// 106.979 us; speedup vs baseline: 1.1510x; 1.1510x over previous
//
#include <hip/hip_runtime.h>

#define NB 2
#define NH 8
#define NS 2048
#define ND 64
#define WKT 32              // keys per wave-tile
#define NTW 16              // tiles per wave per pass (2048 / (32*4))
#define QST 68              // LDS strides (f16 elems; all rows 8B-aligned)
#define KST 76
#define VST 36
#define PST 36
#define OST 68              // f32

typedef _Float16 f16x4 __attribute__((ext_vector_type(4)));
typedef _Float16 f16x8 __attribute__((ext_vector_type(8)));
typedef float    f32x4 __attribute__((ext_vector_type(4)));

#define MFMA16(A,B,C) __builtin_amdgcn_mfma_f32_16x16x32_f16((A),(B),(C),0,0,0)

static __device__ __forceinline__ f16x8 cat8(f16x4 a, f16x4 b) {
    return __builtin_shufflevector(a, b, 0, 1, 2, 3, 4, 5, 6, 7);
}
static __device__ __forceinline__ f16x4 tof16(float4 f) {
    return (f16x4){ (_Float16)f.x, (_Float16)f.y, (_Float16)f.z, (_Float16)f.w };
}
static __device__ __forceinline__ f16x8 lds8(const _Float16* p) {
    f16x4 a = *(const f16x4*)p;          // ds_read_b64 pair
    f16x4 b = *(const f16x4*)(p + 4);
    return cat8(a, b);
}
// wave-local staging fence: wait own LDS ops; pin DS, let VMEM/VALU/MFMA cross
static __device__ __forceinline__ void dsfence() {
    asm volatile("s_waitcnt lgkmcnt(0)");
    __builtin_amdgcn_sched_barrier(0x7F);
}

__global__ __launch_bounds__(256, 2)
void sdpa_kernel(const float* __restrict__ Qg, const float* __restrict__ Kg,
                 const float* __restrict__ Vg, float* __restrict__ Og,
                 float* __restrict__ Ag)
{
    const int tid  = threadIdx.x;
    const int w    = tid >> 6;
    const int lane = tid & 63;
    const int lg   = lane >> 4;
    const int lc   = lane & 15;

    // XCD-pinned decode (proven: FETCH 103->12 MB): bid&7 = XCD, 2 heads per XCD.
    const int bid = blockIdx.x;
    const int xcd = bid & 7;
    const int j   = bid >> 3;           // 0..63
    const int bh  = 2 * xcd + (j >> 5); // 0..15
    const int qt_ = j & 31;             // 0..31

    const size_t base = (size_t)bh * NS * ND;
    const float* Qp = Qg + base + (size_t)qt_ * 64 * ND;
    const float* Kp = Kg + base;
    const float* Vp = Vg + base;
    float*       Op = Og + base + (size_t)qt_ * 64 * ND;
    float*       Ap = Ag + (size_t)bh * NS * NS + (size_t)qt_ * 64 * NS;

    // wave-private regions: Ks[w] 4864 | VT[w] 4608 | Ps[w] 4608; prologue Qs
    // and epilogue Obuf overlay the Ks region; MLs overlays Ps. Total 56320 B.
    __shared__ __align__(16) unsigned char pool[56320];
    _Float16* Qs = (_Float16*)pool;                            // prologue only
    _Float16* Ks = (_Float16*)(pool + (size_t)w * 4864);
    _Float16* VT = (_Float16*)(pool + 19456 + (size_t)w * 4608);
    _Float16* Ps = (_Float16*)(pool + 37888 + (size_t)w * 4608);
    float*   MLs = (float*)(pool + 37888);                     // inter-pass
    float*  Obuf = (float*)pool;                               // epilogue

    // ---- stage Q (scaled by 1/T = 1/8, exact) cooperatively ----
    {
        const int srow = tid >> 4, sd0 = (tid & 15) * 4;
        #pragma unroll
        for (int it = 0; it < 4; ++it) {
            const int r = srow + 16 * it;
            float4 f = *(const float4*)&Qp[(size_t)r * ND + sd0];
            f16x4 h = { (_Float16)(f.x * 0.125f), (_Float16)(f.y * 0.125f),
                        (_Float16)(f.z * 0.125f), (_Float16)(f.w * 0.125f) };
            *(f16x4*)&Qs[r * QST + sd0] = h;
        }
    }
    __syncthreads();
    f16x8 qfa[4], qfb[4];        // every wave needs all 64 q columns
    #pragma unroll
    for (int qt = 0; qt < 4; ++qt) {
        qfa[qt] = lds8(&Qs[(16 * qt + lc) * QST + 8 * lg]);
        qfb[qt] = lds8(&Qs[(16 * qt + lc) * QST + 8 * lg + 32]);
    }
    __syncthreads();             // Qs dead; Ks overlays it

    const int vkq = lane >> 3;   // V staging: key quad 4*vkq
    const int vdg = lane & 7;    // V staging: d group 8*vdg

    float4 kr[8], vr[8];
    auto loadKr = [&](int t) {   // flat-coalesced: 1 KB per instruction
        const int koff = (4 * t + w) * WKT;
        #pragma unroll
        for (int i = 0; i < 8; ++i)
            kr[i] = *(const float4*)&Kp[(size_t)koff * ND + i * 256 + 4 * lane];
    };
    auto writeKs = [&]() {       // cvt (auto vmcnt wait) + ds_write
        #pragma unroll
        for (int i = 0; i < 8; ++i)
            *(f16x4*)&Ks[(4 * i + lg) * KST + 4 * lc] = tof16(kr[i]);
    };
    auto loadVr = [&](int t) {   // keys 4vkq..+3  x  d 8vdg..+7
        const int koff = (4 * t + w) * WKT;
        #pragma unroll
        for (int r = 0; r < 4; ++r)
            #pragma unroll
            for (int h = 0; h < 2; ++h)
                vr[2 * r + h] = *(const float4*)
                    &Vp[(size_t)(koff + 4 * vkq + r) * ND + 8 * vdg + 4 * h];
    };
    auto writeVT = [&]() {       // 4x4 in-register transpose -> b64 writes
        #pragma unroll
        for (int h = 0; h < 2; ++h)
            #pragma unroll
            for (int jj = 0; jj < 4; ++jj) {
                f16x4 col = { (_Float16)vr[0 + h][jj], (_Float16)vr[2 + h][jj],
                              (_Float16)vr[4 + h][jj], (_Float16)vr[6 + h][jj] };
                *(f16x4*)&VT[(8 * vdg + 4 * h + jj) * VST + 4 * vkq] = col;
            }
    };

    float lacc[4] = {0.f, 0.f, 0.f, 0.f};

    // ============ PASS A: denominators (issue-early / write-late) ============
    loadKr(0);
    writeKs();
    for (int t = 0; t < NTW; ++t) {
        loadKr(t + 1 < NTW ? t + 1 : 0);    // issue next-tile loads EARLY
        dsfence();                          // drain my ds_writes (wave-local)

        __builtin_amdgcn_s_setprio(1);
        #pragma unroll
        for (int mt = 0; mt < 2; ++mt) {
            f16x8 a0 = lds8(&Ks[(16 * mt + lc) * KST + 8 * lg]);
            f16x8 a1 = lds8(&Ks[(16 * mt + lc) * KST + 8 * lg + 32]);
            #pragma unroll
            for (int qt = 0; qt < 4; ++qt) {
                f32x4 z = {0.f, 0.f, 0.f, 0.f};
                z = MFMA16(a0, qfa[qt], z);
                z = MFMA16(a1, qfb[qt], z);
                #pragma unroll
                for (int r = 0; r < 4; ++r)
                    lacc[qt] += __expf(z[r]);
            }
        }
        __builtin_amdgcn_s_setprio(0);
        __builtin_amdgcn_sched_barrier(0x7F);   // reads stay before the write-back
        writeKs();                              // write-late: loads had compute-time
    }

    // ---- merge denominators across waves (max-free softmax) ----
    #pragma unroll
    for (int qt = 0; qt < 4; ++qt) {
        lacc[qt] += __shfl_xor(lacc[qt], 16);
        lacc[qt] += __shfl_xor(lacc[qt], 32);
    }
    if (lg == 0) {
        #pragma unroll
        for (int qt = 0; qt < 4; ++qt)
            MLs[w * 64 + 16 * qt + lc] = lacc[qt];
    }
    __syncthreads();
    float il[4];
    #pragma unroll
    for (int qt = 0; qt < 4; ++qt)
        il[qt] = 1.0f / (MLs[16 * qt + lc] + MLs[64 + 16 * qt + lc] +
                         MLs[128 + 16 * qt + lc] + MLs[192 + 16 * qt + lc]);
    __syncthreads();             // MLs dead; Ps overlays it

    // ============ PASS B: attn write + PV (issue-early / write-late) ============
    f32x4 acc[4][4];             // [dt][qt]
    #pragma unroll
    for (int dt = 0; dt < 4; ++dt)
        #pragma unroll
        for (int qt = 0; qt < 4; ++qt)
            acc[dt][qt] = {0.f, 0.f, 0.f, 0.f};

    loadKr(0); loadVr(0);
    writeKs(); writeVT();
    for (int t = 0; t < NTW; ++t) {
        const int koff = (4 * t + w) * WKT;
        {
            const int n = t + 1 < NTW ? t + 1 : 0;
            loadKr(n); loadVr(n);           // issue next-tile loads EARLY
        }
        dsfence();                          // drain my K/VT ds_writes

        f32x4 s[2][4];
        __builtin_amdgcn_s_setprio(1);
        #pragma unroll
        for (int mt = 0; mt < 2; ++mt) {
            f16x8 a0 = lds8(&Ks[(16 * mt + lc) * KST + 8 * lg]);
            f16x8 a1 = lds8(&Ks[(16 * mt + lc) * KST + 8 * lg + 32]);
            #pragma unroll
            for (int qt = 0; qt < 4; ++qt) {
                f32x4 z = {0.f, 0.f, 0.f, 0.f};
                z = MFMA16(a0, qfa[qt], z);
                z = MFMA16(a1, qfb[qt], z);
                s[mt][qt] = z;
            }
        }
        __builtin_amdgcn_s_setprio(0);

        #pragma unroll
        for (int mt = 0; mt < 2; ++mt)
            #pragma unroll
            for (int qt = 0; qt < 4; ++qt) {
                f32x4 p;
                #pragma unroll
                for (int r = 0; r < 4; ++r)
                    p[r] = __expf(s[mt][qt][r]) * il[qt];
                __builtin_nontemporal_store(p,
                    (f32x4*)&Ap[(size_t)(16 * qt + lc) * NS + koff + 16 * mt + 4 * lg]);
                f16x4 ph = { (_Float16)p[0], (_Float16)p[1],
                             (_Float16)p[2], (_Float16)p[3] };
                *(f16x4*)&Ps[(16 * qt + lc) * PST + 16 * mt + 4 * lg] = ph;
            }
        asm volatile("s_waitcnt lgkmcnt(0)" ::: "memory");  // P RAW (wave-local)
        __builtin_amdgcn_sched_barrier(0);

        f16x8 bf[4];
        #pragma unroll
        for (int qt = 0; qt < 4; ++qt)
            bf[qt] = lds8(&Ps[(16 * qt + lc) * PST + 8 * lg]);
        __builtin_amdgcn_s_setprio(1);
        #pragma unroll
        for (int dt = 0; dt < 4; ++dt) {
            f16x8 af = lds8(&VT[(16 * dt + lc) * VST + 8 * lg]);
            #pragma unroll
            for (int qt = 0; qt < 4; ++qt)
                acc[dt][qt] = MFMA16(af, bf[qt], acc[dt][qt]);
        }
        __builtin_amdgcn_s_setprio(0);
        __builtin_amdgcn_sched_barrier(0x7F);   // reads stay before the write-back
        writeKs(); writeVT();                   // write-late staging for t+1
    }

    // ---- merge partial O across waves (sequential LDS accumulate), store ----
    __syncthreads();             // all main-loop LDS dead; Obuf overlays
    #pragma unroll
    for (int ww = 0; ww < 4; ++ww) {
        if (w == ww) {
            #pragma unroll
            for (int dt = 0; dt < 4; ++dt)
                #pragma unroll
                for (int qt = 0; qt < 4; ++qt) {
                    float* ad = &Obuf[(16 * qt + lc) * OST + 16 * dt + 4 * lg];
                    f32x4 v = acc[dt][qt];
                    if (ww > 0) v = v + *(const f32x4*)ad;
                    *(f32x4*)ad = v;
                }
        }
        __syncthreads();
    }
    #pragma unroll
    for (int dt = 0; dt < 4; ++dt) {
        f32x4 o = *(const f32x4*)&Obuf[(16 * w + lc) * OST + 16 * dt + 4 * lg];
        __builtin_nontemporal_store(o,
            (f32x4*)&Op[(size_t)(16 * w + lc) * ND + 16 * dt + 4 * lg]);
    }
}

extern "C" void kernel_launch(void* const* d_in, const int* in_sizes, int n_in,
                              void* d_out, int out_size, void* d_ws, size_t ws_size,
                              hipStream_t stream) {
    const float* q = (const float*)d_in[0];
    const float* k = (const float*)d_in[1];
    const float* v = (const float*)d_in[2];
    float* out  = (float*)d_out;
    float* attn = out + (size_t)NB * NH * NS * ND;  // outputs: (output, attn)

    sdpa_kernel<<<dim3((NS / 64) * NB * NH), 256, 0, stream>>>(q, k, v, out, attn);
}

// Round 13
// 99.486 us; speedup vs baseline: 1.2377x; 1.0753x over previous
//
#include <hip/hip_runtime.h>

#define NB 2
#define NH 8
#define NS 2048
#define ND 64
#define WKT 32              // keys per wave-tile
#define NTW 16              // tiles per wave per pass (2048 / (32*4))
#define QST 68              // LDS strides (f16 elems; all rows 8B-aligned)
#define KST 76
#define VST 36
#define PST 36
#define OST 68              // f32

typedef _Float16 f16x4 __attribute__((ext_vector_type(4)));
typedef _Float16 f16x8 __attribute__((ext_vector_type(8)));
typedef float    f32x4 __attribute__((ext_vector_type(4)));

#define MFMA16(A,B,C) __builtin_amdgcn_mfma_f32_16x16x32_f16((A),(B),(C),0,0,0)

static __device__ __forceinline__ f16x8 cat8(f16x4 a, f16x4 b) {
    return __builtin_shufflevector(a, b, 0, 1, 2, 3, 4, 5, 6, 7);
}
static __device__ __forceinline__ f16x8 lds8(const _Float16* p) {
    f16x4 a = *(const f16x4*)p;          // ds_read_b64 pair
    f16x4 b = *(const f16x4*)(p + 4);
    return cat8(a, b);
}
// wave-local staging fence: wait own LDS ops, block DS reordering only
static __device__ __forceinline__ void dsfence() {
    asm volatile("s_waitcnt lgkmcnt(0)");
    __builtin_amdgcn_sched_barrier(0x7F);
}

__global__ __launch_bounds__(256, 2)
void sdpa_kernel(const float* __restrict__ Qg, const float* __restrict__ Kg,
                 const float* __restrict__ Vg, float* __restrict__ Og,
                 float* __restrict__ Ag)
{
    const int tid  = threadIdx.x;
    const int w    = tid >> 6;
    const int lane = tid & 63;
    const int lg   = lane >> 4;
    const int lc   = lane & 15;

    // XCD-pinned decode (proven: FETCH 103->12 MB): bid&7 = XCD, 2 heads per XCD.
    const int bid = blockIdx.x;
    const int xcd = bid & 7;
    const int j   = bid >> 3;           // 0..63
    const int bh  = 2 * xcd + (j >> 5); // 0..15
    const int qt_ = j & 31;             // 0..31

    const size_t base = (size_t)bh * NS * ND;
    const float* Qp = Qg + base + (size_t)qt_ * 64 * ND;
    const float* Kp = Kg + base;
    const float* Vp = Vg + base;
    float*       Op = Og + base + (size_t)qt_ * 64 * ND;
    float*       Ap = Ag + (size_t)bh * NS * NS + (size_t)qt_ * 64 * NS;

    // wave-private regions: Ks[w] 4864 | VT[w] 4608 | Ps[w] 4608; prologue Qs
    // and epilogue Obuf overlay the Ks region; MLs overlays Ps. Total 56320 B.
    __shared__ __align__(16) unsigned char pool[56320];
    _Float16* Qs = (_Float16*)pool;                            // prologue only
    _Float16* Ks = (_Float16*)(pool + (size_t)w * 4864);
    _Float16* VT = (_Float16*)(pool + 19456 + (size_t)w * 4608);
    _Float16* Ps = (_Float16*)(pool + 37888 + (size_t)w * 4608);
    float*   MLs = (float*)(pool + 37888);                     // inter-pass
    float*  Obuf = (float*)pool;                               // epilogue

    // ---- stage Q (scaled by 1/T = 1/8, exact) cooperatively ----
    {
        const int srow = tid >> 4, sd0 = (tid & 15) * 4;
        #pragma unroll
        for (int it = 0; it < 4; ++it) {
            const int r = srow + 16 * it;
            float4 f = *(const float4*)&Qp[(size_t)r * ND + sd0];
            f16x4 h = { (_Float16)(f.x * 0.125f), (_Float16)(f.y * 0.125f),
                        (_Float16)(f.z * 0.125f), (_Float16)(f.w * 0.125f) };
            *(f16x4*)&Qs[r * QST + sd0] = h;
        }
    }
    __syncthreads();
    f16x8 qfa[4], qfb[4];        // every wave needs all 64 q columns
    #pragma unroll
    for (int qt = 0; qt < 4; ++qt) {
        qfa[qt] = lds8(&Qs[(16 * qt + lc) * QST + 8 * lg]);
        qfb[qt] = lds8(&Qs[(16 * qt + lc) * QST + 8 * lg + 32]);
    }
    __syncthreads();             // Qs dead; Ks overlays it

    const int vkq = lane >> 3;   // V staging: key quad 4*vkq
    const int vdg = lane & 7;    // V staging: d group 8*vdg

    float lacc[4] = {0.f, 0.f, 0.f, 0.f};

    // ============ PASS A: denominators (wave-private, barrier-free) ============
    for (int t = 0; t < NTW; ++t) {
        const int koff = (4 * t + w) * WKT;
        {
            float4 kr[8];        // flat-coalesced: 1 KB per instruction
            #pragma unroll
            for (int i = 0; i < 8; ++i)
                kr[i] = *(const float4*)&Kp[(size_t)koff * ND + i * 256 + 4 * lane];
            #pragma unroll
            for (int i = 0; i < 8; ++i) {
                f16x4 h = { (_Float16)kr[i].x, (_Float16)kr[i].y,
                            (_Float16)kr[i].z, (_Float16)kr[i].w };
                *(f16x4*)&Ks[(4 * i + lg) * KST + 4 * lc] = h;
            }
        }
        dsfence();

        __builtin_amdgcn_s_setprio(1);
        #pragma unroll
        for (int mt = 0; mt < 2; ++mt) {
            f16x8 a0 = lds8(&Ks[(16 * mt + lc) * KST + 8 * lg]);
            f16x8 a1 = lds8(&Ks[(16 * mt + lc) * KST + 8 * lg + 32]);
            #pragma unroll
            for (int qt = 0; qt < 4; ++qt) {
                f32x4 z = {0.f, 0.f, 0.f, 0.f};
                z = MFMA16(a0, qfa[qt], z);
                z = MFMA16(a1, qfb[qt], z);
                #pragma unroll
                for (int r = 0; r < 4; ++r)
                    lacc[qt] += __expf(z[r]);
            }
        }
        __builtin_amdgcn_s_setprio(0);
        __builtin_amdgcn_sched_barrier(0x7F);   // reads stay before next writes
    }

    // ---- merge denominators across waves (max-free softmax) ----
    #pragma unroll
    for (int qt = 0; qt < 4; ++qt) {
        lacc[qt] += __shfl_xor(lacc[qt], 16);
        lacc[qt] += __shfl_xor(lacc[qt], 32);
    }
    if (lg == 0) {
        #pragma unroll
        for (int qt = 0; qt < 4; ++qt)
            MLs[w * 64 + 16 * qt + lc] = lacc[qt];
    }
    __syncthreads();
    float il[4];
    #pragma unroll
    for (int qt = 0; qt < 4; ++qt)
        il[qt] = 1.0f / (MLs[16 * qt + lc] + MLs[64 + 16 * qt + lc] +
                         MLs[128 + 16 * qt + lc] + MLs[192 + 16 * qt + lc]);
    __syncthreads();             // MLs dead; Ps overlays it

    // ============ PASS B: attn write + PV (wave-private, barrier-free) ============
    f32x4 acc[4][4];             // [dt][qt] : O^T partials for this wave's keys
    #pragma unroll
    for (int dt = 0; dt < 4; ++dt)
        #pragma unroll
        for (int qt = 0; qt < 4; ++qt)
            acc[dt][qt] = {0.f, 0.f, 0.f, 0.f};

    for (int t = 0; t < NTW; ++t) {
        const int koff = (4 * t + w) * WKT;
        {
            float4 kr[8];
            #pragma unroll
            for (int i = 0; i < 8; ++i)
                kr[i] = *(const float4*)&Kp[(size_t)koff * ND + i * 256 + 4 * lane];
            #pragma unroll
            for (int i = 0; i < 8; ++i) {
                f16x4 h = { (_Float16)kr[i].x, (_Float16)kr[i].y,
                            (_Float16)kr[i].z, (_Float16)kr[i].w };
                *(f16x4*)&Ks[(4 * i + lg) * KST + 4 * lc] = h;
            }
        }
        {
            float4 vr[8];        // keys 4vkq..+3  x  d 8vdg..+7
            #pragma unroll
            for (int r = 0; r < 4; ++r)
                #pragma unroll
                for (int h = 0; h < 2; ++h)
                    vr[2 * r + h] = *(const float4*)
                        &Vp[(size_t)(koff + 4 * vkq + r) * ND + 8 * vdg + 4 * h];
            #pragma unroll
            for (int h = 0; h < 2; ++h)
                #pragma unroll
                for (int jj = 0; jj < 4; ++jj) {   // 4x4 in-register transpose
                    f16x4 col = { (_Float16)vr[0 + h][jj], (_Float16)vr[2 + h][jj],
                                  (_Float16)vr[4 + h][jj], (_Float16)vr[6 + h][jj] };
                    *(f16x4*)&VT[(8 * vdg + 4 * h + jj) * VST + 4 * vkq] = col;
                }
        }
        dsfence();

        f32x4 s[2][4];
        __builtin_amdgcn_s_setprio(1);
        #pragma unroll
        for (int mt = 0; mt < 2; ++mt) {
            f16x8 a0 = lds8(&Ks[(16 * mt + lc) * KST + 8 * lg]);
            f16x8 a1 = lds8(&Ks[(16 * mt + lc) * KST + 8 * lg + 32]);
            #pragma unroll
            for (int qt = 0; qt < 4; ++qt) {
                f32x4 z = {0.f, 0.f, 0.f, 0.f};
                z = MFMA16(a0, qfa[qt], z);
                z = MFMA16(a1, qfb[qt], z);
                s[mt][qt] = z;
            }
        }
        __builtin_amdgcn_s_setprio(0);

        // p = exp(s)*il -> f16 into Ps ONLY (attn store reads back from Ps)
        #pragma unroll
        for (int mt = 0; mt < 2; ++mt)
            #pragma unroll
            for (int qt = 0; qt < 4; ++qt) {
                f32x4 p;
                #pragma unroll
                for (int r = 0; r < 4; ++r)
                    p[r] = __expf(s[mt][qt][r]) * il[qt];
                f16x4 ph = { (_Float16)p[0], (_Float16)p[1],
                             (_Float16)p[2], (_Float16)p[3] };
                *(f16x4*)&Ps[(16 * qt + lc) * PST + 16 * mt + 4 * lg] = ph;
            }
        dsfence();               // wave-local: P writes visible to own reads

        // PV: O^T += V^T . P^T
        f16x8 bf[4];
        #pragma unroll
        for (int qt = 0; qt < 4; ++qt)
            bf[qt] = lds8(&Ps[(16 * qt + lc) * PST + 8 * lg]);
        __builtin_amdgcn_s_setprio(1);
        #pragma unroll
        for (int dt = 0; dt < 4; ++dt) {
            f16x8 af = lds8(&VT[(16 * dt + lc) * VST + 8 * lg]);
            #pragma unroll
            for (int qt = 0; qt < 4; ++qt)
                acc[dt][qt] = MFMA16(af, bf[qt], acc[dt][qt]);
        }
        __builtin_amdgcn_s_setprio(0);

        // attn store: read back Ps, cvt f16->f32, 1KB-contiguous per instruction
        // (8 q-rows x 128B full aligned lines; off critical path, plain stores)
        #pragma unroll
        for (int i = 0; i < 8; ++i) {
            const int qr = 8 * i + (lane >> 3);
            const int kc = 4 * (lane & 7);
            f16x4 ph = *(const f16x4*)&Ps[qr * PST + kc];
            f32x4 pf = { (float)ph[0], (float)ph[1], (float)ph[2], (float)ph[3] };
            *(f32x4*)&Ap[(size_t)qr * NS + koff + kc] = pf;
        }
        __builtin_amdgcn_sched_barrier(0x7F);   // Ps reads precede next-tile writes
    }

    // ---- merge partial O across waves (sequential LDS accumulate), store ----
    __syncthreads();             // all main-loop LDS dead; Obuf overlays
    #pragma unroll
    for (int ww = 0; ww < 4; ++ww) {
        if (w == ww) {
            #pragma unroll
            for (int dt = 0; dt < 4; ++dt)
                #pragma unroll
                for (int qt = 0; qt < 4; ++qt) {
                    float* ad = &Obuf[(16 * qt + lc) * OST + 16 * dt + 4 * lg];
                    f32x4 v = acc[dt][qt];
                    if (ww > 0) v = v + *(const f32x4*)ad;
                    *(f32x4*)ad = v;
                }
        }
        __syncthreads();
    }
    #pragma unroll
    for (int dt = 0; dt < 4; ++dt) {
        f32x4 o = *(const f32x4*)&Obuf[(16 * w + lc) * OST + 16 * dt + 4 * lg];
        *(f32x4*)&Op[(size_t)(16 * w + lc) * ND + 16 * dt + 4 * lg] = o;
    }
}

extern "C" void kernel_launch(void* const* d_in, const int* in_sizes, int n_in,
                              void* d_out, int out_size, void* d_ws, size_t ws_size,
                              hipStream_t stream) {
    const float* q = (const float*)d_in[0];
    const float* k = (const float*)d_in[1];
    const float* v = (const float*)d_in[2];
    float* out  = (float*)d_out;
    float* attn = out + (size_t)NB * NH * NS * ND;  // outputs: (output, attn)

    sdpa_kernel<<<dim3((NS / 64) * NB * NH), 256, 0, stream>>>(q, k, v, out, attn);
}